// Round 1
// baseline (2548.889 us; speedup 1.0000x reference)
//
#include <hip/hip_runtime.h>

// ---------------- problem constants ----------------
#define T_LEN 128
#define N_CH 64
#define HD 256
#define NBG 64          // batch groups (16 rows each), batch = 1024
// ws layout (bytes)
#define WPACK_OFF 0
#define WPACK_BYTES (2L*8*10*8*64*16)          // 1,310,720
#define BIAS_OFF 1310720
#define XF_OFF 1318912
#define XF_BYTES (64L*128*2*64*16)             // 16,777,216

typedef short bf16x8 __attribute__((ext_vector_type(8)));
typedef float f32x4 __attribute__((ext_vector_type(4)));

__device__ __forceinline__ short f32_to_bf16(float f) {
  unsigned u = __float_as_uint(f);
  unsigned r = u + 0x7FFFu + ((u >> 16) & 1u);   // RNE
  return (short)(r >> 16);
}
__device__ __forceinline__ float sigmoidf_fast(float x) {
  return 1.0f / (1.0f + __expf(-x));
}
__device__ __forceinline__ float tanhf_fast(float x) {
  return 1.0f - 2.0f / (__expf(2.0f * x) + 1.0f);
}

// ---------------- prep: pack W fragment-major ----------------
// Wpack[dir][w][kt][mt][lane][8 bf16]; row = gt*256 + 32w + 16jt + (l&15),
// k = kt*32 + (l>>4)*8 + e  (k<64 -> W_ih, else W_hh col k-64)
__global__ void pack_w(const float* __restrict__ Wih_f, const float* __restrict__ Whh_f,
                       const float* __restrict__ Wih_b, const float* __restrict__ Whh_b,
                       short* __restrict__ wpack) {
  int t = blockIdx.x * blockDim.x + threadIdx.x;   // 81920 exact
  int l = t & 63; t >>= 6;
  int mt = t & 7; t >>= 3;
  int kt = t % 10; t /= 10;
  int w = t & 7;
  int dir = t >> 3;
  const float* Wih = dir ? Wih_b : Wih_f;
  const float* Whh = dir ? Whh_b : Whh_f;
  int gt = mt >> 1, jt = mt & 1;
  int row = gt * 256 + 32 * w + 16 * jt + (l & 15);
  int kbase = kt * 32 + (l >> 4) * 8;
  bf16x8 v;
#pragma unroll
  for (int e = 0; e < 8; ++e) {
    int k = kbase + e;
    float f = (k < 64) ? Wih[row * 64 + k] : Whh[row * 256 + (k - 64)];
    v[e] = f32_to_bf16(f);
  }
  long idx = ((((long)dir * 8 + w) * 10 + kt) * 8 + mt) * 64 + l;
  *reinterpret_cast<bf16x8*>(wpack + idx * 8) = v;
}

__global__ void pack_bias(const float* __restrict__ bihf, const float* __restrict__ bhhf,
                          const float* __restrict__ bihb, const float* __restrict__ bhhb,
                          float* __restrict__ bias) {
  int t = blockIdx.x * blockDim.x + threadIdx.x;
  if (t >= 2048) return;
  int dir = t >> 10, g = t & 1023;
  bias[t] = dir ? (bihb[g] + bhhb[g]) : (bihf[g] + bhhf[g]);
}

// xF[bg][t][kt][lane][8 bf16]: n = a0+(l&15), k(channel) = kt*32+(l>>4)*8+e
__global__ void pack_x(const float* __restrict__ x, short* __restrict__ xf) {
  int t = blockIdx.x * blockDim.x + threadIdx.x;   // 2^20 exact
  int l = t & 63; t >>= 6;
  int kt = t & 1; t >>= 1;
  int tt = t & 127; t >>= 7;
  int bg = t;
  int s = bg >> 2, a0 = (bg & 3) << 4;
  int cbase = kt * 32 + (l >> 4) * 8;
  int a = a0 + (l & 15);
  bf16x8 v;
#pragma unroll
  for (int e = 0; e < 8; ++e) {
    int c = cbase + e;
    v[e] = f32_to_bf16(x[(((long)s * 64 + c) * 128 + tt) * 64 + a]);
  }
  long idx = (((long)bg * 128 + tt) * 2 + kt) * 64 + l;
  *reinterpret_cast<bf16x8*>(xf + idx * 8) = v;
}

// ---------------- the recurrent kernel ----------------
// grid (64 bgroups, 2 dirs), block 512 (8 waves). Wave w owns hidden slice
// [32w, 32w+32) for all 4 gates (8 MFMA N-tiles of 16). D rows = gates,
// D cols = batch (lane&15) -> coalesced out stores. K = 320 = 2 x-tiles + 8 h-tiles.
__global__ __launch_bounds__(512, 2) void lstm_rec(
    const short* __restrict__ wpack, const float* __restrict__ bias,
    const short* __restrict__ xf, float* __restrict__ out) {
  const int bg = blockIdx.x, dir = blockIdx.y;
  const int tid = threadIdx.x;
  const int w = tid >> 6, l = tid & 63;
  const int lg = l >> 4, ln = l & 15;
  const int s = bg >> 2, a0 = (bg & 3) << 4;

  // h double buffer: row = batch a (16 rows x 512B), XOR-swizzled on bits 4-6
  __shared__ __align__(16) short hbuf[2][16 * 256];
  for (int i = tid; i < 16 * 256; i += 512) hbuf[0][i] = 0;

  // bias folded into acc init
  f32x4 bias4[8];
#pragma unroll
  for (int mt = 0; mt < 8; ++mt) {
    int gt = mt >> 1, jt = mt & 1;
#pragma unroll
    for (int r = 0; r < 4; ++r) {
      int row = gt * 256 + 32 * w + 16 * jt + 4 * lg + r;
      bias4[mt][r] = bias[dir * 1024 + row];
    }
  }

  const bf16x8* wp = reinterpret_cast<const bf16x8*>(wpack) +
                     ((long)dir * 8 + w) * 80 * 64 + l;  // + (kt*8+mt)*64
  // persistent W_ih fragments (kt 0,1)
  bf16x8 wih[2][8];
#pragma unroll
  for (int kt = 0; kt < 2; ++kt)
#pragma unroll
    for (int mt = 0; mt < 8; ++mt) wih[kt][mt] = wp[(kt * 8 + mt) * 64];

  const bf16x8* xfb = reinterpret_cast<const bf16x8*>(xf) + (long)bg * 128 * 2 * 64 + l;

  float* outp = out + ((long)s * 512 + dir * 256) * 8192 + a0 + ln;

  float cst[2][4] = {{0.f, 0.f, 0.f, 0.f}, {0.f, 0.f, 0.f, 0.f}};
  const int swz = (ln & 7) << 4;

  // prologue prefetch: first-step x frags + kt2 W stream
  int t0 = dir ? (T_LEN - 1) : 0;
  bf16x8 bx0 = xfb[(t0 * 2 + 0) * 64];
  bf16x8 bx1 = xfb[(t0 * 2 + 1) * 64];
  bf16x8 wstr[2][8];
#pragma unroll
  for (int mt = 0; mt < 8; ++mt) wstr[0][mt] = wp[(2 * 8 + mt) * 64];

  __syncthreads();

  for (int st = 0; st < T_LEN; ++st) {
    int t = dir ? (T_LEN - 1 - st) : st;
    int rbuf = st & 1;

    f32x4 acc[8];
#pragma unroll
    for (int mt = 0; mt < 8; ++mt) acc[mt] = bias4[mt];

    // input projection (K-tiles 0,1), W in registers
#pragma unroll
    for (int mt = 0; mt < 8; ++mt)
      acc[mt] = __builtin_amdgcn_mfma_f32_16x16x32_bf16(wih[0][mt], bx0, acc[mt], 0, 0, 0);
#pragma unroll
    for (int mt = 0; mt < 8; ++mt)
      acc[mt] = __builtin_amdgcn_mfma_f32_16x16x32_bf16(wih[1][mt], bx1, acc[mt], 0, 0, 0);

    // recurrent part: stream W k-tiles 2..9 from L2, depth-2 dbuf
    const char* hb = reinterpret_cast<const char*>(hbuf[rbuf]) + 512 * ln;
#pragma unroll
    for (int kt = 2; kt < 10; ++kt) {
      const int cur = kt & 1;  // kt=2 -> buf 0
      if (kt < 9) {
#pragma unroll
        for (int mt = 0; mt < 8; ++mt) wstr[cur ^ 1][mt] = wp[((kt + 1) * 8 + mt) * 64];
      }
      int boff = (((kt - 2) * 64 + lg * 16) ^ swz);
      bf16x8 bh = *reinterpret_cast<const bf16x8*>(hb + boff);
#pragma unroll
      for (int mt = 0; mt < 8; ++mt)
        acc[mt] = __builtin_amdgcn_mfma_f32_16x16x32_bf16(wstr[cur][mt], bh, acc[mt], 0, 0, 0);
    }

    // epilogue: gates -> c,h ; write h (bf16, swizzled LDS) + out (f32)
    char* hw = reinterpret_cast<char*>(hbuf[rbuf ^ 1]) + 512 * ln;
    float* outt = outp + (long)t * 64;
#pragma unroll
    for (int jt = 0; jt < 2; ++jt) {
#pragma unroll
      for (int r = 0; r < 4; ++r) {
        float gi = sigmoidf_fast(acc[0 + jt][r]);
        float gf = sigmoidf_fast(acc[2 + jt][r]);
        float gg = tanhf_fast(acc[4 + jt][r]);
        float go = sigmoidf_fast(acc[6 + jt][r]);
        float c = gf * cst[jt][r] + gi * gg;
        cst[jt][r] = c;
        float h = go * tanhf_fast(c);
        int j = 32 * w + 16 * jt + 4 * lg + r;
        *reinterpret_cast<short*>(hw + ((2 * j) ^ swz)) = f32_to_bf16(h);
        outt[(long)j * 8192] = h;
      }
    }

    // cross-barrier prefetch for next step (addresses valid: clamped)
    int tn = dir ? (t > 0 ? t - 1 : 0) : (t < T_LEN - 1 ? t + 1 : T_LEN - 1);
    bx0 = xfb[(tn * 2 + 0) * 64];
    bx1 = xfb[(tn * 2 + 1) * 64];
#pragma unroll
    for (int mt = 0; mt < 8; ++mt) wstr[0][mt] = wp[(2 * 8 + mt) * 64];

    __syncthreads();
  }
}

// ---------------- launcher ----------------
extern "C" void kernel_launch(void* const* d_in, const int* in_sizes, int n_in,
                              void* d_out, int out_size, void* d_ws, size_t ws_size,
                              hipStream_t stream) {
  const float* x     = (const float*)d_in[0];
  const float* Wih_f = (const float*)d_in[1];
  const float* Whh_f = (const float*)d_in[2];
  const float* bih_f = (const float*)d_in[3];
  const float* bhh_f = (const float*)d_in[4];
  const float* Wih_b = (const float*)d_in[5];
  const float* Whh_b = (const float*)d_in[6];
  const float* bih_b = (const float*)d_in[7];
  const float* bhh_b = (const float*)d_in[8];
  float* out = (float*)d_out;

  char* ws = (char*)d_ws;
  short* wpack = (short*)(ws + WPACK_OFF);
  float* bias  = (float*)(ws + BIAS_OFF);
  short* xfb   = (short*)(ws + XF_OFF);

  hipLaunchKernelGGL(pack_w, dim3(320), dim3(256), 0, stream,
                     Wih_f, Whh_f, Wih_b, Whh_b, wpack);
  hipLaunchKernelGGL(pack_bias, dim3(8), dim3(256), 0, stream,
                     bih_f, bhh_f, bih_b, bhh_b, bias);
  hipLaunchKernelGGL(pack_x, dim3(4096), dim3(256), 0, stream, x, xfb);
  hipLaunchKernelGGL(lstm_rec, dim3(64, 2), dim3(512), 0, stream,
                     wpack, bias, xfb, out);
}

// Round 2
// 2443.968 us; speedup vs baseline: 1.0429x; 1.0429x over previous
//
#include <hip/hip_runtime.h>

// ---------------- problem constants ----------------
#define T_LEN 128
#define N_CH 64
#define HD 256
#define NBG 64          // batch groups (16 rows each), batch = 1024
// ws layout (bytes)
#define WPACK_OFF 0
#define WPACK_BYTES (2L*8*10*8*64*16)          // 1,310,720
#define BIAS_OFF 1310720
#define XF_OFF 1318912
#define XF_BYTES (64L*128*2*64*16)             // 16,777,216

typedef short bf16x8 __attribute__((ext_vector_type(8)));
typedef float f32x4 __attribute__((ext_vector_type(4)));

__device__ __forceinline__ short f32_to_bf16(float f) {
  unsigned u = __float_as_uint(f);
  unsigned r = u + 0x7FFFu + ((u >> 16) & 1u);   // RNE
  return (short)(r >> 16);
}
__device__ __forceinline__ float sigmoidf_fast(float x) {
  return 1.0f / (1.0f + __expf(-x));
}
__device__ __forceinline__ float tanhf_fast(float x) {
  return 1.0f - 2.0f / (__expf(2.0f * x) + 1.0f);
}

// ---------------- prep: pack W fragment-major ----------------
// Wpack[dir][w][kt][mt][lane][8 bf16]; row = gt*256 + 32w + 16jt + (l&15),
// k = kt*32 + (l>>4)*8 + e  (k<64 -> W_ih, else W_hh col k-64)
__global__ void pack_w(const float* __restrict__ Wih_f, const float* __restrict__ Whh_f,
                       const float* __restrict__ Wih_b, const float* __restrict__ Whh_b,
                       short* __restrict__ wpack) {
  int t = blockIdx.x * blockDim.x + threadIdx.x;   // 81920 exact
  int l = t & 63; t >>= 6;
  int mt = t & 7; t >>= 3;
  int kt = t % 10; t /= 10;
  int w = t & 7;
  int dir = t >> 3;
  const float* Wih = dir ? Wih_b : Wih_f;
  const float* Whh = dir ? Whh_b : Whh_f;
  int gt = mt >> 1, jt = mt & 1;
  int row = gt * 256 + 32 * w + 16 * jt + (l & 15);
  int kbase = kt * 32 + (l >> 4) * 8;
  bf16x8 v;
#pragma unroll
  for (int e = 0; e < 8; ++e) {
    int k = kbase + e;
    float f = (k < 64) ? Wih[row * 64 + k] : Whh[row * 256 + (k - 64)];
    v[e] = f32_to_bf16(f);
  }
  long idx = ((((long)dir * 8 + w) * 10 + kt) * 8 + mt) * 64 + l;
  *reinterpret_cast<bf16x8*>(wpack + idx * 8) = v;
}

__global__ void pack_bias(const float* __restrict__ bihf, const float* __restrict__ bhhf,
                          const float* __restrict__ bihb, const float* __restrict__ bhhb,
                          float* __restrict__ bias) {
  int t = blockIdx.x * blockDim.x + threadIdx.x;
  if (t >= 2048) return;
  int dir = t >> 10, g = t & 1023;
  bias[t] = dir ? (bihb[g] + bhhb[g]) : (bihf[g] + bhhf[g]);
}

// xF[bg][t][kt][lane][8 bf16]: n = a0+(l&15), k(channel) = kt*32+(l>>4)*8+e
__global__ void pack_x(const float* __restrict__ x, short* __restrict__ xf) {
  int t = blockIdx.x * blockDim.x + threadIdx.x;   // 2^20 exact
  int l = t & 63; t >>= 6;
  int kt = t & 1; t >>= 1;
  int tt = t & 127; t >>= 7;
  int bg = t;
  int s = bg >> 2, a0 = (bg & 3) << 4;
  int cbase = kt * 32 + (l >> 4) * 8;
  int a = a0 + (l & 15);
  bf16x8 v;
#pragma unroll
  for (int e = 0; e < 8; ++e) {
    int c = cbase + e;
    v[e] = f32_to_bf16(x[(((long)s * 64 + c) * 128 + tt) * 64 + a]);
  }
  long idx = (((long)bg * 128 + tt) * 2 + kt) * 64 + l;
  *reinterpret_cast<bf16x8*>(xf + idx * 8) = v;
}

// ---------------- the recurrent kernel ----------------
// grid 128 (bid&1 = dir so each XCD L2 caches one dir's W), block 512 (8 waves).
// Wave w owns hidden slice [32w, 32w+32) for all 4 gates (8 MFMA M-tiles of 16).
// D rows = gates, D cols = batch (lane&15) -> coalesced out stores.
// K = 320 = 2 x-tiles (W_ih, register-persistent) + 8 h-tiles (streamed from L2).
// __launch_bounds__(512, 1): 1 block/CU -> 256-VGPR budget; live state ~196 VGPR
// (wih 64 + wstr 64 + acc 32 + cst/bx/addr ~36) -> no scratch spill (the R1 bug).
__global__ __launch_bounds__(512, 1) void lstm_rec(
    const short* __restrict__ wpack, const float* __restrict__ bias,
    const short* __restrict__ xf, float* __restrict__ out) {
  const int bid = blockIdx.x;
  const int dir = bid & 1, bg = bid >> 1;
  const int tid = threadIdx.x;
  const int w = tid >> 6, l = tid & 63;
  const int lg = l >> 4, ln = l & 15;
  const int s = bg >> 2, a0 = (bg & 3) << 4;

  // h double buffer: row = batch a (16 rows x 512B), XOR-swizzled on bits 4-6
  __shared__ __align__(16) short hbuf[2][16 * 256];
  // bias staged in LDS (frees 32 VGPRs vs register-resident bias4)
  __shared__ __align__(16) f32x4 bias_lds[256];   // [w][lg][mt]
  for (int i = tid; i < 16 * 256; i += 512) hbuf[0][i] = 0;
  for (int i = tid; i < 1024; i += 512) {
    int r = i & 3, mt = (i >> 2) & 7, lg_ = (i >> 5) & 3, w_ = i >> 7;
    int gt = mt >> 1, jt = mt & 1;
    int row = gt * 256 + 32 * w_ + 16 * jt + 4 * lg_ + r;
    reinterpret_cast<float*>(bias_lds)[i] = bias[dir * 1024 + row];
  }

  const bf16x8* wp = reinterpret_cast<const bf16x8*>(wpack) +
                     ((long)dir * 8 + w) * 80 * 64 + l;  // + (kt*8+mt)*64
  // persistent W_ih fragments (kt 0,1)
  bf16x8 wih[2][8];
#pragma unroll
  for (int kt = 0; kt < 2; ++kt)
#pragma unroll
    for (int mt = 0; mt < 8; ++mt) wih[kt][mt] = wp[(kt * 8 + mt) * 64];

  const bf16x8* xfb = reinterpret_cast<const bf16x8*>(xf) + (long)bg * 128 * 2 * 64 + l;

  float* outp = out + ((long)s * 512 + dir * 256) * 8192 + a0 + ln;

  float cst[2][4] = {{0.f, 0.f, 0.f, 0.f}, {0.f, 0.f, 0.f, 0.f}};
  const int swz = (ln & 7) << 4;
  const int bias_idx = ((w << 2) | lg) << 3;

  // prologue prefetch: first-step x frags + kt2 W stream
  int t0 = dir ? (T_LEN - 1) : 0;
  bf16x8 bx0 = xfb[(t0 * 2 + 0) * 64];
  bf16x8 bx1 = xfb[(t0 * 2 + 1) * 64];
  bf16x8 wstr[2][8];
#pragma unroll
  for (int mt = 0; mt < 8; ++mt) wstr[0][mt] = wp[(2 * 8 + mt) * 64];

  __syncthreads();

  for (int st = 0; st < T_LEN; ++st) {
    int t = dir ? (T_LEN - 1 - st) : st;
    int rbuf = st & 1;

    f32x4 acc[8];
#pragma unroll
    for (int mt = 0; mt < 8; ++mt) acc[mt] = bias_lds[bias_idx + mt];

    // input projection (K-tiles 0,1), W in registers
#pragma unroll
    for (int mt = 0; mt < 8; ++mt)
      acc[mt] = __builtin_amdgcn_mfma_f32_16x16x32_bf16(wih[0][mt], bx0, acc[mt], 0, 0, 0);
#pragma unroll
    for (int mt = 0; mt < 8; ++mt)
      acc[mt] = __builtin_amdgcn_mfma_f32_16x16x32_bf16(wih[1][mt], bx1, acc[mt], 0, 0, 0);

    // recurrent part: stream W k-tiles 2..9 from L2, depth-2 dbuf
    const char* hb = reinterpret_cast<const char*>(hbuf[rbuf]) + 512 * ln;
#pragma unroll
    for (int kt = 2; kt < 10; ++kt) {
      const int cur = kt & 1;  // kt=2 -> buf 0
      if (kt < 9) {
#pragma unroll
        for (int mt = 0; mt < 8; ++mt) wstr[cur ^ 1][mt] = wp[((kt + 1) * 8 + mt) * 64];
      }
      int boff = (((kt - 2) * 64 + lg * 16) ^ swz);
      bf16x8 bh = *reinterpret_cast<const bf16x8*>(hb + boff);
#pragma unroll
      for (int mt = 0; mt < 8; ++mt)
        acc[mt] = __builtin_amdgcn_mfma_f32_16x16x32_bf16(wstr[cur][mt], bh, acc[mt], 0, 0, 0);
    }

    // epilogue: gates -> c,h ; write h (bf16, swizzled LDS) + out (f32)
    char* hw = reinterpret_cast<char*>(hbuf[rbuf ^ 1]) + 512 * ln;
    float* outt = outp + (long)t * 64;
#pragma unroll
    for (int jt = 0; jt < 2; ++jt) {
#pragma unroll
      for (int r = 0; r < 4; ++r) {
        float gi = sigmoidf_fast(acc[0 + jt][r]);
        float gf = sigmoidf_fast(acc[2 + jt][r]);
        float gg = tanhf_fast(acc[4 + jt][r]);
        float go = sigmoidf_fast(acc[6 + jt][r]);
        float c = gf * cst[jt][r] + gi * gg;
        cst[jt][r] = c;
        float h = go * tanhf_fast(c);
        int j = 32 * w + 16 * jt + 4 * lg + r;
        *reinterpret_cast<short*>(hw + ((2 * j) ^ swz)) = f32_to_bf16(h);
        outt[(long)j * 8192] = h;
      }
    }

    // cross-barrier prefetch for next step (addresses valid: clamped)
    int tn = dir ? (t > 0 ? t - 1 : 0) : (t < T_LEN - 1 ? t + 1 : T_LEN - 1);
    bx0 = xfb[(tn * 2 + 0) * 64];
    bx1 = xfb[(tn * 2 + 1) * 64];
#pragma unroll
    for (int mt = 0; mt < 8; ++mt) wstr[0][mt] = wp[(2 * 8 + mt) * 64];

    __syncthreads();
  }
}

// ---------------- launcher ----------------
extern "C" void kernel_launch(void* const* d_in, const int* in_sizes, int n_in,
                              void* d_out, int out_size, void* d_ws, size_t ws_size,
                              hipStream_t stream) {
  const float* x     = (const float*)d_in[0];
  const float* Wih_f = (const float*)d_in[1];
  const float* Whh_f = (const float*)d_in[2];
  const float* bih_f = (const float*)d_in[3];
  const float* bhh_f = (const float*)d_in[4];
  const float* Wih_b = (const float*)d_in[5];
  const float* Whh_b = (const float*)d_in[6];
  const float* bih_b = (const float*)d_in[7];
  const float* bhh_b = (const float*)d_in[8];
  float* out = (float*)d_out;

  char* ws = (char*)d_ws;
  short* wpack = (short*)(ws + WPACK_OFF);
  float* bias  = (float*)(ws + BIAS_OFF);
  short* xfb   = (short*)(ws + XF_OFF);

  hipLaunchKernelGGL(pack_w, dim3(320), dim3(256), 0, stream,
                     Wih_f, Whh_f, Wih_b, Whh_b, wpack);
  hipLaunchKernelGGL(pack_bias, dim3(8), dim3(256), 0, stream,
                     bih_f, bhh_f, bih_b, bhh_b, bias);
  hipLaunchKernelGGL(pack_x, dim3(4096), dim3(256), 0, stream, x, xfb);
  hipLaunchKernelGGL(lstm_rec, dim3(128), dim3(512), 0, stream,
                     wpack, bias, xfb, out);
}

// Round 3
// 1190.257 us; speedup vs baseline: 2.1415x; 2.0533x over previous
//
#include <hip/hip_runtime.h>

// ---------------- problem constants ----------------
#define T_LEN 128
// ws layout (bytes)
#define WPACK_OFF 0
#define BIAS_OFF 1310720
#define XF_OFF 1318912

typedef short bf16x8 __attribute__((ext_vector_type(8)));
typedef float f32x4 __attribute__((ext_vector_type(4)));

// ---- LDS layout (bytes), dynamic shared ----
#define L_WRING 0         // 4 ring slots * 8 waves * 4KB = 131072
#define L_X     131072    // 8 waves * 2KB = 16384
#define L_H     147456    // 16 rows * 512B = 8192 (single-buffered)
#define L_BIAS  155648    // 4096
#define L_SCR   159744    // 1024 (prologue dummy-DMA target, never read)
#define SMEM_BYTES 160768

#define WAITV(n) asm volatile("s_waitcnt vmcnt(" #n ")" ::: "memory")

__device__ __forceinline__ short f32_to_bf16(float f) {
  unsigned u = __float_as_uint(f);
  unsigned r = u + 0x7FFFu + ((u >> 16) & 1u);   // RNE
  return (short)(r >> 16);
}
__device__ __forceinline__ float sigmoidf_fast(float x) {
  return 1.0f / (1.0f + __expf(-x));
}
__device__ __forceinline__ float tanhf_fast(float x) {
  return 1.0f - 2.0f / (__expf(2.0f * x) + 1.0f);
}

// async 16B/lane global->LDS DMA (wave-uniform LDS base + lane*16)
__device__ __forceinline__ void gll16(const void* g, char* lds_generic) {
  __builtin_amdgcn_global_load_lds(
      (const __attribute__((address_space(1))) void*)g,
      (__attribute__((address_space(3))) void*)lds_generic, 16, 0, 0);
}

// ---------------- prep: pack W fragment-major ----------------
// Wpack[dir][w][kt][mt][lane][8 bf16]; row = gt*256 + 32w + 16jt + (l&15),
// k = kt*32 + (l>>4)*8 + e  (k<64 -> W_ih, else W_hh col k-64)
__global__ void pack_w(const float* __restrict__ Wih_f, const float* __restrict__ Whh_f,
                       const float* __restrict__ Wih_b, const float* __restrict__ Whh_b,
                       short* __restrict__ wpack) {
  int t = blockIdx.x * blockDim.x + threadIdx.x;   // 81920 exact
  int l = t & 63; t >>= 6;
  int mt = t & 7; t >>= 3;
  int kt = t % 10; t /= 10;
  int w = t & 7;
  int dir = t >> 3;
  const float* Wih = dir ? Wih_b : Wih_f;
  const float* Whh = dir ? Whh_b : Whh_f;
  int gt = mt >> 1, jt = mt & 1;
  int row = gt * 256 + 32 * w + 16 * jt + (l & 15);
  int kbase = kt * 32 + (l >> 4) * 8;
  bf16x8 v;
#pragma unroll
  for (int e = 0; e < 8; ++e) {
    int k = kbase + e;
    float f = (k < 64) ? Wih[row * 64 + k] : Whh[row * 256 + (k - 64)];
    v[e] = f32_to_bf16(f);
  }
  long idx = ((((long)dir * 8 + w) * 10 + kt) * 8 + mt) * 64 + l;
  *reinterpret_cast<bf16x8*>(wpack + idx * 8) = v;
}

__global__ void pack_bias(const float* __restrict__ bihf, const float* __restrict__ bhhf,
                          const float* __restrict__ bihb, const float* __restrict__ bhhb,
                          float* __restrict__ bias) {
  int t = blockIdx.x * blockDim.x + threadIdx.x;
  if (t >= 2048) return;
  int dir = t >> 10, g = t & 1023;
  bias[t] = dir ? (bihb[g] + bhhb[g]) : (bihf[g] + bhhf[g]);
}

// xF[bg][t][kt][lane][8 bf16]: n = a0+(l&15), k(channel) = kt*32+(l>>4)*8+e
__global__ void pack_x(const float* __restrict__ x, short* __restrict__ xf) {
  int t = blockIdx.x * blockDim.x + threadIdx.x;   // 2^20 exact
  int l = t & 63; t >>= 6;
  int kt = t & 1; t >>= 1;
  int tt = t & 127; t >>= 7;
  int bg = t;
  int s = bg >> 2, a0 = (bg & 3) << 4;
  int cbase = kt * 32 + (l >> 4) * 8;
  int a = a0 + (l & 15);
  bf16x8 v;
#pragma unroll
  for (int e = 0; e < 8; ++e) {
    int c = cbase + e;
    v[e] = f32_to_bf16(x[(((long)s * 64 + c) * 128 + tt) * 64 + a]);
  }
  long idx = (((long)bg * 128 + tt) * 2 + kt) * 64 + l;
  *reinterpret_cast<bf16x8*>(xf + idx * 8) = v;
}

// ---------------- the recurrent kernel ----------------
// grid 128 (bid&1 = dir -> each XCD's L2 caches one dir's 640KB W pack),
// block 512 (8 waves). Wave w owns hidden slice [32w,32w+32) of all 4 gates.
// Per step: 20 W half-kt granules (4 x 1KB gll DMA each) + 1 x-granule (2 ops),
// consumed h-tiles (kt2..9) first, x-tiles (kt0,1) last. Ring depth 4, lookahead
// 2 granules, counted vmcnt (never 0 in the loop). W ring is wave-private ->
// no barriers for it; only 2 barriers/step for the single h buffer.
__global__ __launch_bounds__(512) void lstm_rec(
    const short* __restrict__ wpack, const float* __restrict__ bias,
    const short* __restrict__ xf, float* __restrict__ out) {
  extern __shared__ char smem[];
  const int bid = blockIdx.x;
  const int dir = bid & 1, bg = bid >> 1;
  const int tid = threadIdx.x;
  const int w = tid >> 6, l = tid & 63;
  const int lg = l >> 4, ln = l & 15;
  const int s = bg >> 2, a0 = (bg & 3) << 4;

  // zero h, fill bias table
  for (int i = tid; i < 4096; i += 512) ((short*)(smem + L_H))[i] = 0;
  for (int i = tid; i < 1024; i += 512) {
    int r = i & 3, mt = (i >> 2) & 7, lg_ = (i >> 5) & 3, w_ = i >> 7;
    int gt = mt >> 1, jt = mt & 1;
    int row = gt * 256 + 32 * w_ + 16 * jt + 4 * lg_ + r;
    ((float*)(smem + L_BIAS))[i] = bias[dir * 1024 + row];
  }
  __syncthreads();   // before any DMA: its vmcnt(0) drain is harmless here

  // per-wave W slice base (fragment-major; +l*16 = this lane's 16B)
  const char* wbase = (const char*)wpack + ((long)dir * 8 + w) * 81920 + (long)l * 16;
  const char* xbase = (const char*)xf + (long)bg * (128L * 2048) + (long)l * 16;
  char* const wring = smem + L_WRING + w * 4096;   // + slot*32768 + m*1024
  char* const xslot = smem + L_X + w * 2048;       // + j*1024

  float* outp = out + ((long)s * 512 + dir * 256) * 8192 + a0 + ln;
  float cst[2][4] = {{0.f, 0.f, 0.f, 0.f}, {0.f, 0.f, 0.f, 0.f}};
  const int swz = (ln & 7) << 4;
  const int bias_off = ((w << 2) | lg) << 7;   // byte offset of this thread's 8 f32x4

  // W granule wg (0..19): wg<16 -> kt=2+(wg>>1); else kt=(wg-16)>>1; half=wg&1
  // issue = 4 gll ops; ring slot = wg&3.
#define ISSUE_W(wg_) do {                                               \
    const int kt_ = ((wg_) < 16) ? (2 + ((wg_) >> 1)) : (((wg_) - 16) >> 1); \
    const int hf_ = (wg_) & 1;                                          \
    _Pragma("unroll")                                                   \
    for (int m_ = 0; m_ < 4; ++m_)                                      \
      gll16(wbase + (kt_ * 8 + hf_ * 4 + m_) * 1024,                    \
            wring + ((wg_) & 3) * 32768 + m_ * 1024);                   \
  } while (0)

  // prologue: granules g0,g1 + 8 dummy ops (mimic steady-state store slots)
  ISSUE_W(0);
  ISSUE_W(1);
#pragma unroll
  for (int m = 0; m < 8; ++m) gll16(wbase + m * 1024, smem + L_SCR);

  for (int st = 0; st < T_LEN; ++st) {
    const int t = dir ? (T_LEN - 1 - st) : st;

    // acc init = bias (LDS broadcast reads)
    f32x4 acc[8];
#pragma unroll
    for (int mt = 0; mt < 8; ++mt)
      acc[mt] = *reinterpret_cast<const f32x4*>(smem + L_BIAS + bias_off + mt * 16);

    bf16x8 bh, bx;
#pragma unroll
    for (int c = 0; c < 20; ++c) {
      // ---- issue phase (lookahead 2 granules) ----
      if (c <= 13) { ISSUE_W(c + 2); }
      else if (c == 14) {   // x-data granule for THIS step (consumed at c=16..19)
        gll16(xbase + ((long)t * 2 + 0) * 1024, xslot + 0);
        gll16(xbase + ((long)t * 2 + 1) * 1024, xslot + 1024);
      } else if (c == 15) { ISSUE_W(16); ISSUE_W(17); }
      else if (c == 16) { ISSUE_W(18); }
      else if (c == 17) { ISSUE_W(19); }
      else if (c == 18) { ISSUE_W(0); }   // next step's g0 (step-invariant addr)
      else              { ISSUE_W(1); }   // next step's g1
      // ---- counted wait: newest-2-granules (+stores around step seam) ----
      switch (c) {
        case 0: case 1: WAITV(16); break;   // + 8 out-stores + ng0/ng1 in flight
        case 14: WAITV(6); break;           // next = g15(4)+g16(2)
        case 15: WAITV(10); break;          // next = g16(2)+g17(4)+g18(4)
        default: WAITV(8); break;
      }
      __builtin_amdgcn_sched_barrier(0);
      // ---- consume: 4 W frags from ring slot c&3 ----
      bf16x8 wa[4];
#pragma unroll
      for (int m = 0; m < 4; ++m)
        wa[m] = *reinterpret_cast<const bf16x8*>(
            wring + (c & 3) * 32768 + m * 1024 + l * 16);
      if (c < 16) {
        if ((c & 1) == 0)   // one h B-frag per kt, reused by both halves
          bh = *reinterpret_cast<const bf16x8*>(
              smem + L_H + 512 * ln + (((c >> 1) * 64 + lg * 16) ^ swz));
#pragma unroll
        for (int m = 0; m < 4; ++m)
          acc[(c & 1) * 4 + m] =
              __builtin_amdgcn_mfma_f32_16x16x32_bf16(wa[m], bh, acc[(c & 1) * 4 + m], 0, 0, 0);
      } else {
        if ((c & 1) == 0)   // bx0 at c16 (kt0), bx1 at c18 (kt1)
          bx = *reinterpret_cast<const bf16x8*>(xslot + ((c - 16) >> 1) * 1024 + l * 16);
#pragma unroll
        for (int m = 0; m < 4; ++m)
          acc[(c & 1) * 4 + m] =
              __builtin_amdgcn_mfma_f32_16x16x32_bf16(wa[m], bx, acc[(c & 1) * 4 + m], 0, 0, 0);
      }
    }

    // ---- epilogue: gates -> c,h ----
    float hval[2][4];
#pragma unroll
    for (int jt = 0; jt < 2; ++jt) {
#pragma unroll
      for (int r = 0; r < 4; ++r) {
        float gi = sigmoidf_fast(acc[0 + jt][r]);
        float gf = sigmoidf_fast(acc[2 + jt][r]);
        float gg = tanhf_fast(acc[4 + jt][r]);
        float go = sigmoidf_fast(acc[6 + jt][r]);
        float cc = gf * cst[jt][r] + gi * gg;
        cst[jt][r] = cc;
        hval[jt][r] = go * tanhf_fast(cc);
      }
    }

    // barrier A: all waves done reading h(t-1) (their reads fed MFMAs already)
    __builtin_amdgcn_sched_barrier(0);
    __builtin_amdgcn_s_barrier();
    __builtin_amdgcn_sched_barrier(0);

    // write h (bf16, swizzled LDS) + out (f32)
    char* hw = smem + L_H + 512 * ln;
    float* outt = outp + (long)t * 64;
#pragma unroll
    for (int jt = 0; jt < 2; ++jt) {
#pragma unroll
      for (int r = 0; r < 4; ++r) {
        int j = 32 * w + 16 * jt + 4 * lg + r;
        *reinterpret_cast<short*>(hw + ((2 * j) ^ swz)) = f32_to_bf16(hval[jt][r]);
        outt[(long)j * 8192] = hval[jt][r];
      }
    }

    // barrier B: h visible before next step's reads
    asm volatile("s_waitcnt lgkmcnt(0)" ::: "memory");
    __builtin_amdgcn_s_barrier();
    __builtin_amdgcn_sched_barrier(0);
  }
#undef ISSUE_W
}

// ---------------- launcher ----------------
extern "C" void kernel_launch(void* const* d_in, const int* in_sizes, int n_in,
                              void* d_out, int out_size, void* d_ws, size_t ws_size,
                              hipStream_t stream) {
  const float* x     = (const float*)d_in[0];
  const float* Wih_f = (const float*)d_in[1];
  const float* Whh_f = (const float*)d_in[2];
  const float* bih_f = (const float*)d_in[3];
  const float* bhh_f = (const float*)d_in[4];
  const float* Wih_b = (const float*)d_in[5];
  const float* Whh_b = (const float*)d_in[6];
  const float* bih_b = (const float*)d_in[7];
  const float* bhh_b = (const float*)d_in[8];
  float* out = (float*)d_out;

  char* ws = (char*)d_ws;
  short* wpack = (short*)(ws + WPACK_OFF);
  float* bias  = (float*)(ws + BIAS_OFF);
  short* xfb   = (short*)(ws + XF_OFF);

  static int smem_set = 0;
  if (!smem_set) {
    (void)hipFuncSetAttribute((const void*)lstm_rec,
                              hipFuncAttributeMaxDynamicSharedMemorySize, SMEM_BYTES);
    smem_set = 1;
  }

  hipLaunchKernelGGL(pack_w, dim3(320), dim3(256), 0, stream,
                     Wih_f, Whh_f, Wih_b, Whh_b, wpack);
  hipLaunchKernelGGL(pack_bias, dim3(8), dim3(256), 0, stream,
                     bih_f, bhh_f, bih_b, bhh_b, bias);
  hipLaunchKernelGGL(pack_x, dim3(4096), dim3(256), 0, stream, x, xfb);
  hipLaunchKernelGGL(lstm_rec, dim3(128), dim3(512), SMEM_BYTES, stream,
                     wpack, bias, xfb, out);
}